// Round 1
// baseline (144.622 us; speedup 1.0000x reference)
//
#include <hip/hip_runtime.h>

#define B_ 32
#define H_ 4
#define S_ 4096
#define M_ 128
#define EPS_ 1e-8f

// ---------------------------------------------------------------------------
// Kernel 1: score[b,h,s] = beta[b,h]/max(||k_bh||,eps) * dot(k_bh, mem_bs) / max(||mem_bs||,eps)
// Layout: wave = 4 rows x 16 lanes; lane i covers columns [i*8, i*8+8).
// k fragments live in registers (fixed per lane); butterfly reduce over 16-lane groups.
// ---------------------------------------------------------------------------
#define ST1 128  // rows of S per block

__global__ __launch_bounds__(256) void k_scores(
    const float* __restrict__ mem, const float* __restrict__ kk,
    const float* __restrict__ beta, float* __restrict__ sc)
{
  const int b   = blockIdx.y;
  const int s0  = blockIdx.x * ST1;
  const int tid = threadIdx.x;
  const int wv   = tid >> 6;
  const int lane = tid & 63;
  const int g    = lane >> 4;   // row-in-quad
  const int i    = lane & 15;   // column-group

  // per-lane k fragments: k[h][i*8 .. i*8+8)
  float4 ka[H_], kb[H_];
  const float* kbase = kk + b * H_ * M_ + i * 8;
#pragma unroll
  for (int h = 0; h < H_; ++h) {
    ka[h] = *(const float4*)(kbase + h * M_);
    kb[h] = *(const float4*)(kbase + h * M_ + 4);
  }

  // coef[h] = beta / max(||k_h||, eps) — redundant per block, trivial cost
  float coef[H_];
#pragma unroll
  for (int h = 0; h < H_; ++h) {
    float sq = ka[h].x*ka[h].x + ka[h].y*ka[h].y + ka[h].z*ka[h].z + ka[h].w*ka[h].w
             + kb[h].x*kb[h].x + kb[h].y*kb[h].y + kb[h].z*kb[h].z + kb[h].w*kb[h].w;
#pragma unroll
    for (int msk = 1; msk < 16; msk <<= 1) sq += __shfl_xor(sq, msk, 64);
    float kn = fmaxf(sqrtf(sq), EPS_);
    coef[h] = beta[b * H_ + h] / kn;
  }
  const float cw = (i == 0) ? coef[0] : (i == 1) ? coef[1] : (i == 2) ? coef[2] : coef[3];

  for (int it = 0; it < ST1 / 16; ++it) {
    const int s = s0 + it * 16 + wv * 4 + g;
    const float* row = mem + ((size_t)(b * S_ + s)) * M_ + i * 8;
    const float4 v0 = *(const float4*)(row);
    const float4 v1 = *(const float4*)(row + 4);

    float sq = v0.x*v0.x + v0.y*v0.y + v0.z*v0.z + v0.w*v0.w
             + v1.x*v1.x + v1.y*v1.y + v1.z*v1.z + v1.w*v1.w;
    float d[H_];
#pragma unroll
    for (int h = 0; h < H_; ++h) {
      d[h] = v0.x*ka[h].x + v0.y*ka[h].y + v0.z*ka[h].z + v0.w*ka[h].w
           + v1.x*kb[h].x + v1.y*kb[h].y + v1.z*kb[h].z + v1.w*kb[h].w;
    }
#pragma unroll
    for (int msk = 1; msk < 16; msk <<= 1) {
      sq += __shfl_xor(sq, msk, 64);
#pragma unroll
      for (int h = 0; h < H_; ++h) d[h] += __shfl_xor(d[h], msk, 64);
    }
    const float mn = fmaxf(sqrtf(sq), EPS_);
    if (i < H_) {
      const float dv = (i == 0) ? d[0] : (i == 1) ? d[1] : (i == 2) ? d[2] : d[3];
      sc[((size_t)(b * H_ + i)) * S_ + s] = dv * cw / mn;
    }
  }
}

// ---------------------------------------------------------------------------
// Kernel 2: in-place softmax over S per (b,h). One block per (b,h).
// ---------------------------------------------------------------------------
__global__ __launch_bounds__(256) void k_softmax(float* __restrict__ sc)
{
  const int bh = blockIdx.x;
  float* p = sc + (size_t)bh * S_;
  const int tid = threadIdx.x;
  const int wv = tid >> 6, lane = tid & 63;

  float v[S_ / 256];
  float mx = -1e30f;
#pragma unroll
  for (int j = 0; j < S_ / 256; ++j) { v[j] = p[tid + j * 256]; mx = fmaxf(mx, v[j]); }

  __shared__ float redm[4];
#pragma unroll
  for (int off = 32; off >= 1; off >>= 1) mx = fmaxf(mx, __shfl_xor(mx, off, 64));
  if (lane == 0) redm[wv] = mx;
  __syncthreads();
  mx = fmaxf(fmaxf(redm[0], redm[1]), fmaxf(redm[2], redm[3]));

  float sum = 0.f;
#pragma unroll
  for (int j = 0; j < S_ / 256; ++j) { v[j] = __expf(v[j] - mx); sum += v[j]; }
  __shared__ float reds[4];
#pragma unroll
  for (int off = 32; off >= 1; off >>= 1) sum += __shfl_xor(sum, off, 64);
  if (lane == 0) reds[wv] = sum;
  __syncthreads();
  sum = reds[0] + reds[1] + reds[2] + reds[3];

  const float inv = 1.0f / sum;
#pragma unroll
  for (int j = 0; j < S_ / 256; ++j) p[tid + j * 256] = v[j] * inv;
}

// ---------------------------------------------------------------------------
// Kernel 3: nmem computed in-flight (sequential per-head erase/add), reading
// accumulated via fp32 atomics. Thread t: m = t&127, row-parity = t>>7.
// ---------------------------------------------------------------------------
#define ST3 256  // rows of S per block

__global__ __launch_bounds__(256) void k_writeread(
    const float* __restrict__ mem, const float* __restrict__ w,
    const float* __restrict__ er, const float* __restrict__ ad,
    float* __restrict__ out)
{
  const int b   = blockIdx.y;
  const int s0  = blockIdx.x * ST3;
  const int tid = threadIdx.x;

  __shared__ float se[H_ * M_];
  __shared__ float sa[H_ * M_];
  __shared__ float sw[H_ * ST3];

  for (int idx = tid; idx < H_ * M_; idx += 256) {
    se[idx] = er[b * H_ * M_ + idx];
    sa[idx] = ad[b * H_ * M_ + idx];
  }
  for (int idx = tid; idx < H_ * ST3; idx += 256) {
    const int h = idx / ST3, r = idx % ST3;
    sw[idx] = w[((size_t)(b * H_ + h)) * S_ + s0 + r];
  }
  __syncthreads();

  const int m = tid & 127, half = tid >> 7;
  const float e0 = se[0 * M_ + m], e1 = se[1 * M_ + m], e2 = se[2 * M_ + m], e3 = se[3 * M_ + m];
  const float a0 = sa[0 * M_ + m], a1 = sa[1 * M_ + m], a2 = sa[2 * M_ + m], a3 = sa[3 * M_ + m];

  float acc0 = 0.f, acc1 = 0.f, acc2 = 0.f, acc3 = 0.f;
  for (int it = 0; it < ST3 / 2; ++it) {
    const int r = it * 2 + half;
    const int s = s0 + r;
    const float mv = mem[((size_t)(b * S_ + s)) * M_ + m];
    const float w0 = sw[0 * ST3 + r], w1 = sw[1 * ST3 + r], w2 = sw[2 * ST3 + r], w3 = sw[3 * ST3 + r];
    float x = mv;
    x = x * (1.f - w0 * e0) + w0 * a0;
    x = x * (1.f - w1 * e1) + w1 * a1;
    x = x * (1.f - w2 * e2) + w2 * a2;
    x = x * (1.f - w3 * e3) + w3 * a3;
    acc0 += w0 * x; acc1 += w1 * x; acc2 += w2 * x; acc3 += w3 * x;
  }

  float* ob = out + (size_t)b * H_ * M_ + m;
  atomicAdd(ob + 0 * M_, acc0);
  atomicAdd(ob + 1 * M_, acc1);
  atomicAdd(ob + 2 * M_, acc2);
  atomicAdd(ob + 3 * M_, acc3);
}

extern "C" void kernel_launch(void* const* d_in, const int* in_sizes, int n_in,
                              void* d_out, int out_size, void* d_ws, size_t ws_size,
                              hipStream_t stream) {
  const float* mem  = (const float*)d_in[0];
  const float* kk   = (const float*)d_in[1];
  const float* beta = (const float*)d_in[2];
  const float* er   = (const float*)d_in[3];
  const float* ad   = (const float*)d_in[4];
  float* out = (float*)d_out;
  float* sc  = (float*)d_ws;  // (B,H,S) scores -> weights, 2 MiB

  hipMemsetAsync(out, 0, (size_t)out_size * sizeof(float), stream);

  dim3 g1(S_ / ST1, B_);
  k_scores<<<g1, 256, 0, stream>>>(mem, kk, beta, sc);

  k_softmax<<<B_ * H_, 256, 0, stream>>>(sc);

  dim3 g3(S_ / ST3, B_);
  k_writeread<<<g3, 256, 0, stream>>>(mem, sc, er, ad, out);
}

// Round 2
// 130.950 us; speedup vs baseline: 1.1044x; 1.1044x over previous
//
#include <hip/hip_runtime.h>

#define B_ 32
#define H_ 4
#define S_ 4096
#define M_ 128
#define EPS_ 1e-8f

// ---------------------------------------------------------------------------
// Kernel 1: u[b,h,s] = exp(beta/||k|| * dot(k, mem_s)/||mem_s||)  (no max-sub:
// arg in (-1,1) since beta in [0,1), |cossim|<=1). Also atomicAdd per-(b,h)
// partial sums into Z. Layout: 8 lanes/row x 8 rows/wave; lane owns 16 cols;
// butterfly over 3 rounds x 5 values per 8 rows. Coalesced store via LDS.
// ---------------------------------------------------------------------------
#define ST1 128  // rows of S per block

__global__ __launch_bounds__(256) void k_scores(
    const float* __restrict__ mem, const float* __restrict__ kk,
    const float* __restrict__ beta, float* __restrict__ sc,
    float* __restrict__ Z)
{
  const int b   = blockIdx.y;
  const int s0  = blockIdx.x * ST1;
  const int tid = threadIdx.x;
  const int wv   = tid >> 6;
  const int lane = tid & 63;
  const int g    = lane >> 3;   // row-in-wave (0..7)
  const int i    = lane & 7;    // column-group (16 cols each)

  // per-lane k fragments: cols [i*16, i*16+16) for each head
  float4 kf[H_][4];
  const float* kbase = kk + b * H_ * M_ + i * 16;
#pragma unroll
  for (int h = 0; h < H_; ++h)
#pragma unroll
    for (int q = 0; q < 4; ++q)
      kf[h][q] = *(const float4*)(kbase + h * M_ + q * 4);

  float coef[H_];
#pragma unroll
  for (int h = 0; h < H_; ++h) {
    float sq = 0.f;
#pragma unroll
    for (int q = 0; q < 4; ++q)
      sq += kf[h][q].x*kf[h][q].x + kf[h][q].y*kf[h][q].y
          + kf[h][q].z*kf[h][q].z + kf[h][q].w*kf[h][q].w;
#pragma unroll
    for (int msk = 1; msk < 8; msk <<= 1) sq += __shfl_xor(sq, msk, 64);
    coef[h] = beta[b * H_ + h] / fmaxf(sqrtf(sq), EPS_);
  }
  const float cw = (i == 0) ? coef[0] : (i == 1) ? coef[1] : (i == 2) ? coef[2] : coef[3];

  __shared__ float su[ST1 * 5];  // [row][head], pad 5 (stride-5 is conflict-free)

  for (int it = 0; it < ST1 / 32; ++it) {
    const int rloc = it * 32 + wv * 8 + g;
    const int s = s0 + rloc;
    const float* row = mem + ((size_t)(b * S_ + s)) * M_ + i * 16;
    float4 v[4];
#pragma unroll
    for (int q = 0; q < 4; ++q) v[q] = *(const float4*)(row + q * 4);

    float sq = 0.f;
    float d[H_] = {0.f, 0.f, 0.f, 0.f};
#pragma unroll
    for (int q = 0; q < 4; ++q) {
      sq += v[q].x*v[q].x + v[q].y*v[q].y + v[q].z*v[q].z + v[q].w*v[q].w;
#pragma unroll
      for (int h = 0; h < H_; ++h)
        d[h] += v[q].x*kf[h][q].x + v[q].y*kf[h][q].y
              + v[q].z*kf[h][q].z + v[q].w*kf[h][q].w;
    }
#pragma unroll
    for (int msk = 1; msk < 8; msk <<= 1) {
      sq += __shfl_xor(sq, msk, 64);
#pragma unroll
      for (int h = 0; h < H_; ++h) d[h] += __shfl_xor(d[h], msk, 64);
    }
    if (i < H_) {
      const float dv = (i == 0) ? d[0] : (i == 1) ? d[1] : (i == 2) ? d[2] : d[3];
      const float mn = fmaxf(sqrtf(sq), EPS_);
      su[rloc * 5 + i] = __expf(dv * cw / mn);
    }
  }
  __syncthreads();

  // per-head block partial sum: wave wv handles head wv (H_ == 4 waves)
  float vsum = su[lane * 5 + wv] + su[(lane + 64) * 5 + wv];
#pragma unroll
  for (int msk = 1; msk < 64; msk <<= 1) vsum += __shfl_xor(vsum, msk, 64);
  if (lane == 0) atomicAdd(&Z[b * H_ + wv], vsum);

  // coalesced store: wave h stores 128 contiguous floats of head h
  const int h = tid >> 6, j = tid & 63;
  float* dst = sc + ((size_t)(b * H_ + h)) * S_ + s0;
  dst[j]      = su[j * 5 + h];
  dst[j + 64] = su[(j + 64) * 5 + h];
}

// ---------------------------------------------------------------------------
// Kernel 2: second pass over memory. w = u/Z staged in LDS; nmem computed
// in-flight (sequential per-head erase/add); float4 global loads; block-level
// LDS reduction of the per-head reading accumulators, then few atomics.
// ---------------------------------------------------------------------------
#define ST3 256  // rows of S per block

__global__ __launch_bounds__(256) void k_writeread(
    const float* __restrict__ mem, const float* __restrict__ sc,
    const float* __restrict__ Z, const float* __restrict__ er,
    const float* __restrict__ ad, float* __restrict__ out)
{
  const int b   = blockIdx.y;
  const int s0  = blockIdx.x * ST3;
  const int tid = threadIdx.x;

  __shared__ float sw[H_ * ST3];   // normalized weights for this S-block
  __shared__ float red[4 * 512];   // per-wave partial reading

  float iz[H_];
#pragma unroll
  for (int h = 0; h < H_; ++h) iz[h] = 1.0f / Z[b * H_ + h];

  for (int idx = tid; idx < H_ * ST3; idx += 256) {
    const int h = idx >> 8, r = idx & (ST3 - 1);
    sw[idx] = sc[((size_t)(b * H_ + h)) * S_ + s0 + r] * iz[h];
  }
  __syncthreads();

  const int c  = tid & 31;   // column group: cols [4c, 4c+4)
  const int rr = tid >> 5;   // row slot (0..7)

  float4 e4[H_], a4[H_];
  const int base = b * H_ * M_ + c * 4;
#pragma unroll
  for (int h = 0; h < H_; ++h) {
    e4[h] = *(const float4*)(er + base + h * M_);
    a4[h] = *(const float4*)(ad + base + h * M_);
  }

  float4 acc[H_];
#pragma unroll
  for (int h = 0; h < H_; ++h) acc[h] = make_float4(0.f, 0.f, 0.f, 0.f);

  for (int it = 0; it < ST3 / 8; ++it) {
    const int r = it * 8 + rr;
    const int s = s0 + r;
    float4 x = *(const float4*)(mem + ((size_t)(b * S_ + s)) * M_ + c * 4);
    const float w0 = sw[0 * ST3 + r], w1 = sw[1 * ST3 + r];
    const float w2 = sw[2 * ST3 + r], w3 = sw[3 * ST3 + r];

    x.x = x.x * (1.f - w0 * e4[0].x) + w0 * a4[0].x;
    x.y = x.y * (1.f - w0 * e4[0].y) + w0 * a4[0].y;
    x.z = x.z * (1.f - w0 * e4[0].z) + w0 * a4[0].z;
    x.w = x.w * (1.f - w0 * e4[0].w) + w0 * a4[0].w;
    x.x = x.x * (1.f - w1 * e4[1].x) + w1 * a4[1].x;
    x.y = x.y * (1.f - w1 * e4[1].y) + w1 * a4[1].y;
    x.z = x.z * (1.f - w1 * e4[1].z) + w1 * a4[1].z;
    x.w = x.w * (1.f - w1 * e4[1].w) + w1 * a4[1].w;
    x.x = x.x * (1.f - w2 * e4[2].x) + w2 * a4[2].x;
    x.y = x.y * (1.f - w2 * e4[2].y) + w2 * a4[2].y;
    x.z = x.z * (1.f - w2 * e4[2].z) + w2 * a4[2].z;
    x.w = x.w * (1.f - w2 * e4[2].w) + w2 * a4[2].w;
    x.x = x.x * (1.f - w3 * e4[3].x) + w3 * a4[3].x;
    x.y = x.y * (1.f - w3 * e4[3].y) + w3 * a4[3].y;
    x.z = x.z * (1.f - w3 * e4[3].z) + w3 * a4[3].z;
    x.w = x.w * (1.f - w3 * e4[3].w) + w3 * a4[3].w;

    acc[0].x += w0 * x.x; acc[0].y += w0 * x.y; acc[0].z += w0 * x.z; acc[0].w += w0 * x.w;
    acc[1].x += w1 * x.x; acc[1].y += w1 * x.y; acc[1].z += w1 * x.z; acc[1].w += w1 * x.w;
    acc[2].x += w2 * x.x; acc[2].y += w2 * x.y; acc[2].z += w2 * x.z; acc[2].w += w2 * x.w;
    acc[3].x += w3 * x.x; acc[3].y += w3 * x.y; acc[3].z += w3 * x.z; acc[3].w += w3 * x.w;
  }

  // reduce rr pairs within each wave (lanes 0..31 keep the pair sum)
#pragma unroll
  for (int h = 0; h < H_; ++h) {
    acc[h].x += __shfl_xor(acc[h].x, 32, 64);
    acc[h].y += __shfl_xor(acc[h].y, 32, 64);
    acc[h].z += __shfl_xor(acc[h].z, 32, 64);
    acc[h].w += __shfl_xor(acc[h].w, 32, 64);
  }
  const int wv = tid >> 6, lane = tid & 63;
  if (lane < 32) {
#pragma unroll
    for (int h = 0; h < H_; ++h) {
      red[wv * 512 + (h * 4 + 0) * 32 + lane] = acc[h].x;
      red[wv * 512 + (h * 4 + 1) * 32 + lane] = acc[h].y;
      red[wv * 512 + (h * 4 + 2) * 32 + lane] = acc[h].z;
      red[wv * 512 + (h * 4 + 3) * 32 + lane] = acc[h].w;
    }
  }
  __syncthreads();

  for (int j = tid; j < 512; j += 256) {
    const float val = red[j] + red[512 + j] + red[1024 + j] + red[1536 + j];
    const int h = j >> 7, comp = (j >> 5) & 3, cc = j & 31;
    atomicAdd(&out[b * H_ * M_ + h * M_ + cc * 4 + comp], val);
  }
}

extern "C" void kernel_launch(void* const* d_in, const int* in_sizes, int n_in,
                              void* d_out, int out_size, void* d_ws, size_t ws_size,
                              hipStream_t stream) {
  const float* mem  = (const float*)d_in[0];
  const float* kk   = (const float*)d_in[1];
  const float* beta = (const float*)d_in[2];
  const float* er   = (const float*)d_in[3];
  const float* ad   = (const float*)d_in[4];
  float* out = (float*)d_out;
  float* sc  = (float*)d_ws;                       // (B,H,S) unnormalized exp-scores, 2 MiB
  float* Z   = (float*)((char*)d_ws + (size_t)B_ * H_ * S_ * sizeof(float));  // (B,H)

  hipMemsetAsync(out, 0, (size_t)out_size * sizeof(float), stream);
  hipMemsetAsync(Z, 0, (size_t)B_ * H_ * sizeof(float), stream);

  dim3 g1(S_ / ST1, B_);
  k_scores<<<g1, 256, 0, stream>>>(mem, kk, beta, sc, Z);

  dim3 g3(S_ / ST3, B_);
  k_writeread<<<g3, 256, 0, stream>>>(mem, sc, Z, er, ad, out);
}